// Round 26
// baseline (59.841 us; speedup 1.0000x reference)
//
#include <hip/hip_runtime.h>
#include <stdint.h>
#include <float.h>

// Chamfer distance, B=4, N=M=4096, 3D fp32.
// Outputs (flat, float32): [0] loss, [1..16384] idx12 (float), [16385..32768] idx21.
//
// SEMANTIC CONTRACT (validated R14-R25, absmax 0.0 — do not change):
//   d in f64: d = fma(dx,dx, fma(dy,dy, dz*dz)), dx = x - bx (f64-promoted f32)
//   pick = smallest index j with d_j <= fma(TOL_K(dir), a2 + b2_j, dmin)
//     (a2, b2_j in f64 from promoted f32 coords)
//   K12 = 0.6*2^-23, K21 = 0.   dmin = exact f64 min.
//   Prefilter (R16-proven): every contract-band qualifier has
//     d32 <= fma(2e-7, a2f+b2f_j, me), me = m*(1+2e-6), m = global f32 min,
//     and hence d32 <= skipthr = (me + 7e-7*a2f)*(1+4e-6)  [R18 bound].
//
// R26: per-split CHAMPIONS. min32 tracks per (point,split): champion
// (min d32, first-occurrence argmin j) and runner-up d32. Select needs no
// global rescan: candidate set = champions of splits with champD<=skipthr
// UNION full rescan of splits with runnerUp<=skipthr (provably complete:
// any band qualifier passing prefilter is champion-or-above-runnerup; extras
// fail the contract test; dmin over any superset containing the true f64
// argmin is bitwise unchanged). Select = 1 thread/point, LDS panel, O(32)
// register work + ~1 bb4 gather. Rescan path = verbatim R24 walk (rare).

constexpr int B_ = 4;
constexpr int N_ = 4096;
constexpr int PTS = 256;
constexpr int PPT = 4;                   // points per thread (min32)
constexpr int TILES = N_ / (PTS * PPT);  // 4
constexpr int JSPLIT = 32;
constexpr int CHUNK = N_ / JSPLIT;       // 128
constexpr int SPB = 128;                 // select: points per block
constexpr double EPS32 = 1.1920928955078125e-7;  // 2^-23
constexpr double TOL_K12 = 0.6 * EPS32;
constexpr double TOL_K21 = 0.0;
constexpr double BETA_ = 1.0;
constexpr double GAMMA_ = 1.0;
constexpr double DELTA_ = 0.0;

// grid: (TILES*B_*2, JSPLIT)
__global__ __launch_bounds__(256) void cd_min32(
        const float* __restrict__ xyz1, const float* __restrict__ xyz2,
        float* __restrict__ champD, unsigned int* __restrict__ champJ,
        float* __restrict__ runUp, float4* __restrict__ b4) {
    const int tile  = blockIdx.x % TILES;
    const int b     = (blockIdx.x / TILES) % B_;
    const int dir   = blockIdx.x / (TILES * B_);
    const int split = blockIdx.y;
    const float* A  = dir ? xyz2 : xyz1;
    const float* Bc = dir ? xyz1 : xyz2;
    const size_t ob = (size_t)dir * B_ + b;

    __shared__ float4 s[CHUNK];          // 2 KiB
    const float* bbase = Bc + ((size_t)b * N_ + (size_t)split * CHUNK) * 3;
    if (threadIdx.x < CHUNK) {
        int j = threadIdx.x;
        float bx = bbase[3 * j], by = bbase[3 * j + 1], bz = bbase[3 * j + 2];
        float b2 = bx * bx + by * by + bz * bz;   // prefilter-only (margin ok)
        float4 v = make_float4(bx, by, bz, b2);
        s[j] = v;
        if (tile == 0)                    // one writer per (dir,b,split)
            b4[ob * N_ + (size_t)split * CHUNK + j] = v;
    }
    __syncthreads();

    float px[PPT], py[PPT], pz[PPT];
    float cur[PPT], ruv[PPT];
    unsigned int cj[PPT];
    #pragma unroll
    for (int pi = 0; pi < PPT; ++pi) {
        const int p = tile * (PTS * PPT) + pi * PTS + threadIdx.x;
        const float* ap = A + ((size_t)b * N_ + p) * 3;
        px[pi] = ap[0]; py[pi] = ap[1]; pz[pi] = ap[2];
        cur[pi] = FLT_MAX; ruv[pi] = FLT_MAX; cj[pi] = 0u;
    }

    #pragma unroll 4
    for (int j = 0; j < CHUNK; ++j) {
        float4 bv = s[j];
        const unsigned int jg = (unsigned int)(split * CHUNK + j);
        #pragma unroll
        for (int pi = 0; pi < PPT; ++pi) {
            float dx = px[pi] - bv.x, dy = py[pi] - bv.y, dz = pz[pi] - bv.z;
            float d = __fmaf_rn(dx, dx, __fmaf_rn(dy, dy, dz * dz));
            // invariant cur <= ruv; ascending j + strict < = first-occurrence
            ruv[pi] = fminf(ruv[pi], fmaxf(d, cur[pi]));
            if (d < cur[pi]) cj[pi] = jg;
            cur[pi] = fminf(cur[pi], d);
        }
    }

    const size_t sm = (ob * JSPLIT + split) * N_;
    #pragma unroll
    for (int pi = 0; pi < PPT; ++pi) {
        const int p = tile * (PTS * PPT) + pi * PTS + threadIdx.x;
        champD[sm + p] = cur[pi];
        champJ[sm + p] = cj[pi];
        runUp[sm + p]  = ruv[pi];
    }
}

// one THREAD per point; grid: 2*B_*(N_/SPB) = 256 blocks of SPB=128 threads
__global__ __launch_bounds__(SPB) void cd_select(
        const float* __restrict__ xyz1, const float* __restrict__ xyz2,
        const float* __restrict__ champD, const unsigned int* __restrict__ champJ,
        const float* __restrict__ runUp, const float4* __restrict__ b4,
        double* __restrict__ dminArr, float* __restrict__ out) {
    const int ob  = blockIdx.x >> 5;                 // 32 blocks per (dir,b)
    const int c   = blockIdx.x & 31;
    const int dir = ob >> 2;
    const int b   = ob & 3;
    const int p0  = c * SPB;
    const float* A  = dir ? xyz2 : xyz1;
    const double tolk = dir ? TOL_K21 : TOL_K12;
    const float4* bb4 = b4 + (size_t)ob * N_;

    __shared__ float cDl[JSPLIT][SPB];               // 16 KiB
    __shared__ unsigned int cJl[JSPLIT][SPB];        // 16 KiB
    __shared__ float rul[JSPLIT][SPB];               // 16 KiB

    const int t = threadIdx.x;
    for (int idx = t; idx < JSPLIT * SPB; idx += SPB) {
        const int s = idx >> 7, p = idx & (SPB - 1); // coalesced row loads
        const size_t g = ((size_t)ob * JSPLIT + s) * N_ + p0 + p;
        cDl[s][p] = champD[g];
        cJl[s][p] = champJ[g];
        rul[s][p] = runUp[g];
    }
    __syncthreads();

    const int p = p0 + t;
    const float* ap = A + ((size_t)b * N_ + p) * 3;
    const float x = ap[0], y = ap[1], z = ap[2];
    const float a2f = x * x + y * y + z * z;

    float m = FLT_MAX;
    #pragma unroll
    for (int s = 0; s < JSPLIT; ++s)
        m = fminf(m, cDl[s][t]);                     // == global f32 min

    const float me = __fmaf_rn(2e-6f, m, m);         // m*(1+2e-6)
    const float skipthr = (me + 7e-7f * a2f) * (1.0f + 4e-6f);

    unsigned int candmask = 0, rescmask = 0;
    #pragma unroll
    for (int s = 0; s < JSPLIT; ++s) {
        if (cDl[s][t] <= skipthr) candmask |= (1u << s);
        if (rul[s][t] <= skipthr) rescmask |= (1u << s);
    }

    const double xd = (double)x, yd = (double)y, zd = (double)z;
    const double a2 = xd * xd + yd * yd + zd * zd;

    // pass A: dmin over {champions of cand splits} U {rescan-split survivors}
    double dmin = 1.0e300;
    unsigned int mk = candmask;
    while (mk) {
        int s = __ffs(mk) - 1; mk &= mk - 1;
        float4 bv = bb4[cJl[s][t]];
        double ddx = xd - (double)bv.x, ddy = yd - (double)bv.y,
               ddz = zd - (double)bv.z;
        dmin = fmin(dmin, fma(ddx, ddx, fma(ddy, ddy, ddz * ddz)));
    }
    mk = rescmask;
    while (mk) {                                     // rare: verbatim R24 walk
        int s = __ffs(mk) - 1; mk &= mk - 1;
        for (int j = s * CHUNK; j < (s + 1) * CHUNK; ++j) {
            float4 bv = bb4[j];
            float dx = x - bv.x, dy = y - bv.y, dz = z - bv.z;
            float d32 = __fmaf_rn(dx, dx, __fmaf_rn(dy, dy, dz * dz));
            float thr = __fmaf_rn(2e-7f, a2f + bv.w, me);
            if (d32 <= thr) {
                double ddx = xd - (double)bv.x, ddy = yd - (double)bv.y,
                       ddz = zd - (double)bv.z;
                dmin = fmin(dmin, fma(ddx, ddx, fma(ddy, ddy, ddz * ddz)));
            }
        }
    }

    // pass B: contract pick over the same set (extras provably fail the test)
    unsigned int pick = 0xFFFFFFFFu;
    mk = candmask;
    while (mk) {
        int s = __ffs(mk) - 1; mk &= mk - 1;
        unsigned int j = cJl[s][t];
        float4 bv = bb4[j];
        double bxd = (double)bv.x, byd = (double)bv.y, bzd = (double)bv.z;
        double ddx = xd - bxd, ddy = yd - byd, ddz = zd - bzd;
        double d64 = fma(ddx, ddx, fma(ddy, ddy, ddz * ddz));
        double M   = a2 + (bxd * bxd + byd * byd + bzd * bzd);
        if (d64 <= fma(tolk, M, dmin)) pick = (j < pick) ? j : pick;
    }
    mk = rescmask;
    while (mk) {
        int s = __ffs(mk) - 1; mk &= mk - 1;
        for (int j = s * CHUNK; j < (s + 1) * CHUNK; ++j) {
            float4 bv = bb4[j];
            float dx = x - bv.x, dy = y - bv.y, dz = z - bv.z;
            float d32 = __fmaf_rn(dx, dx, __fmaf_rn(dy, dy, dz * dz));
            float thr = __fmaf_rn(2e-7f, a2f + bv.w, me);
            if (d32 <= thr) {
                double bxd = (double)bv.x, byd = (double)bv.y, bzd = (double)bv.z;
                double ddx = xd - bxd, ddy = yd - byd, ddz = zd - bzd;
                double d64 = fma(ddx, ddx, fma(ddy, ddy, ddz * ddz));
                double M   = a2 + (bxd * bxd + byd * byd + bzd * bzd);
                if (d64 <= fma(tolk, M, dmin))
                    pick = ((unsigned int)j < pick) ? (unsigned int)j : pick;
            }
        }
    }

    dminArr[(size_t)ob * N_ + p] = dmin;
    const size_t obase = (dir == 0) ? (1 + (size_t)b * N_)
                                    : (1 + (size_t)B_ * N_ + (size_t)b * N_);
    out[obase + p] = (float)pick;
}

__global__ __launch_bounds__(256) void cd_finalize(
        const double* __restrict__ dminArr, float* __restrict__ out,
        double* __restrict__ loss_part) {
    const int b = blockIdx.x;
    const int t = threadIdx.x;

    double sum12 = 0.0, max12 = -1.0e300, sum21 = 0.0;
    for (int n = t; n < N_; n += 256) {
        double d12 = dminArr[(size_t)b * N_ + n];
        double d21 = dminArr[((size_t)B_ + b) * N_ + n];
        sum12 += d12;
        max12 = fmax(max12, d12);
        sum21 += d21;
    }
    __shared__ double s1[256], s2[256], s3[256];
    s1[t] = sum12; s2[t] = max12; s3[t] = sum21;
    __syncthreads();
    for (int off = 128; off > 0; off >>= 1) {
        if (t < off) {
            s1[t] += s1[t + off];
            s2[t]  = fmax(s2[t], s2[t + off]);
            s3[t] += s3[t + off];
        }
        __syncthreads();
    }
    if (t == 0) {
        loss_part[b] = s1[0] / (double)N_ + BETA_ * s2[0]
                     + (GAMMA_ + DELTA_ * (double)N_) * (s3[0] / (double)N_);
    }
}

__global__ void cd_loss(const double* __restrict__ loss_part,
                        float* __restrict__ out) {
    if (blockIdx.x == 0 && threadIdx.x == 0) {
        double s = 0.0;
        for (int b = 0; b < B_; ++b) s += loss_part[b];  // fixed order
        out[0] = (float)(s / (double)B_);
    }
}

extern "C" void kernel_launch(void* const* d_in, const int* in_sizes, int n_in,
                              void* d_out, int out_size, void* d_ws, size_t ws_size,
                              hipStream_t stream) {
    const float* xyz1 = (const float*)d_in[0];
    const float* xyz2 = (const float*)d_in[1];
    float* out = (float*)d_out;

    const size_t NP = (size_t)2 * B_ * N_;       // 32768 points
    double* dminArr   = (double*)d_ws;           // NP doubles (256 KiB)
    double* loss_part = dminArr + NP;            // B_ doubles
    float4* b4 = (float4*)(loss_part + B_);      // NP float4 (512 KiB)
    float* champD = (float*)(b4 + NP);           // NP*JSPLIT f32 (4 MiB)
    unsigned int* champJ = (unsigned int*)(champD + NP * JSPLIT);  // 4 MiB
    float* runUp = (float*)(champJ + NP * JSPLIT);                 // 4 MiB

    dim3 grid(TILES * B_ * 2, JSPLIT);
    cd_min32<<<grid, PTS, 0, stream>>>(xyz1, xyz2, champD, champJ, runUp, b4);

    cd_select<<<(int)(NP / SPB), SPB, 0, stream>>>(
        xyz1, xyz2, champD, champJ, runUp, b4, dminArr, out);

    cd_finalize<<<B_, 256, 0, stream>>>(dminArr, out, loss_part);
    cd_loss<<<1, 64, 0, stream>>>(loss_part, out);
}

// Round 27
// 52.459 us; speedup vs baseline: 1.1407x; 1.1407x over previous
//
#include <hip/hip_runtime.h>
#include <stdint.h>
#include <float.h>

// Chamfer distance, B=4, N=M=4096, 3D fp32.
// Outputs (flat, float32): [0] loss, [1..16384] idx12 (float), [16385..32768] idx21.
//
// SEMANTIC CONTRACT (validated R14-R26, absmax 0.0 — do not change):
//   d in f64: d = fma(dx,dx, fma(dy,dy, dz*dz)), dx = x - bx (f64-promoted f32)
//   pick = smallest index j with d_j <= fma(TOL_K(dir), a2 + b2_j, dmin)
//     (a2, b2_j in f64 from promoted f32 coords)
//   K12 = 0.6*2^-23, K21 = 0.   dmin = exact f64 min (true argmin provably in
//   candidate set). Candidate superset extras provably fail the contract test.
//
// R27: min32 ops 11 -> 8/pair. Screening distance t = b2 - 2ab (3 FMA; a2
// const/point, ordering preserved up to cancellation noise ~4e-7*M) + champion
// (cmp+cndmask) + runner-up (fmax+fmin) + cur fmin. Select-side margins widened
// to absorb t-noise: skipthr = fma(4e-6, a2f+|mind|, mind) (~28x the contract
// band; extras ~0 since top-2 gaps >> window); rescan prefilter
// thr = fma(2e-7, a2f+b2_j, skipthr). Completeness: any band qualifier is its
// split's champion (-> candidate) or >= runner-up (-> split rescanned).
// Champion t-ties force ruv=champD -> rescan, so tie semantics are free.
// All candidates get verbatim exact-f64 contract evaluation -> outputs
// bit-identical. PPT 4->2 (grid 2048 = 8 blocks/CU, full wave cap).

constexpr int B_ = 4;
constexpr int N_ = 4096;
constexpr int PTS = 256;
constexpr int PPT = 2;                   // points per thread (min32)
constexpr int TILES = N_ / (PTS * PPT);  // 8
constexpr int JSPLIT = 32;
constexpr int CHUNK = N_ / JSPLIT;       // 128
constexpr int SPB = 128;                 // select: points per block
constexpr double EPS32 = 1.1920928955078125e-7;  // 2^-23
constexpr double TOL_K12 = 0.6 * EPS32;
constexpr double TOL_K21 = 0.0;
constexpr double BETA_ = 1.0;
constexpr double GAMMA_ = 1.0;
constexpr double DELTA_ = 0.0;

// grid: (TILES*B_*2, JSPLIT)
__global__ __launch_bounds__(256) void cd_min32(
        const float* __restrict__ xyz1, const float* __restrict__ xyz2,
        float* __restrict__ champD, unsigned int* __restrict__ champJ,
        float* __restrict__ runUp, float4* __restrict__ b4) {
    const int tile  = blockIdx.x % TILES;
    const int b     = (blockIdx.x / TILES) % B_;
    const int dir   = blockIdx.x / (TILES * B_);
    const int split = blockIdx.y;
    const float* A  = dir ? xyz2 : xyz1;
    const float* Bc = dir ? xyz1 : xyz2;
    const size_t ob = (size_t)dir * B_ + b;

    __shared__ float4 s[CHUNK];          // 2 KiB {bx,by,bz,b2}
    const float* bbase = Bc + ((size_t)b * N_ + (size_t)split * CHUNK) * 3;
    if (threadIdx.x < CHUNK) {
        int j = threadIdx.x;
        float bx = bbase[3 * j], by = bbase[3 * j + 1], bz = bbase[3 * j + 2];
        float b2 = bx * bx + by * by + bz * bz;
        float4 v = make_float4(bx, by, bz, b2);
        s[j] = v;
        if (tile == 0)                    // one writer per (dir,b,split)
            b4[ob * N_ + (size_t)split * CHUNK + j] = v;
    }
    __syncthreads();

    float m2x[PPT], m2y[PPT], m2z[PPT];
    float cur[PPT], ruv[PPT];
    unsigned int cj[PPT];
    #pragma unroll
    for (int pi = 0; pi < PPT; ++pi) {
        const int p = tile * (PTS * PPT) + pi * PTS + threadIdx.x;
        const float* ap = A + ((size_t)b * N_ + p) * 3;
        m2x[pi] = -2.0f * ap[0];         // exact (x2)
        m2y[pi] = -2.0f * ap[1];
        m2z[pi] = -2.0f * ap[2];
        cur[pi] = FLT_MAX; ruv[pi] = FLT_MAX; cj[pi] = 0u;
    }

    #pragma unroll 4
    for (int j = 0; j < CHUNK; ++j) {
        float4 bv = s[j];
        const unsigned int jg = (unsigned int)(split * CHUNK + j);
        #pragma unroll
        for (int pi = 0; pi < PPT; ++pi) {
            // screening distance (3 FMA): t = b2 - 2ab  (per-point a2 omitted)
            float t = __fmaf_rn(m2x[pi], bv.x,
                      __fmaf_rn(m2y[pi], bv.y,
                      __fmaf_rn(m2z[pi], bv.z, bv.w)));
            ruv[pi] = fminf(ruv[pi], fmaxf(t, cur[pi]));   // runner-up
            if (t < cur[pi]) cj[pi] = jg;                  // champion idx
            cur[pi] = fminf(cur[pi], t);
        }
    }

    const size_t sm = (ob * JSPLIT + split) * N_;
    #pragma unroll
    for (int pi = 0; pi < PPT; ++pi) {
        const int p = tile * (PTS * PPT) + pi * PTS + threadIdx.x;
        champD[sm + p] = cur[pi];        // t-space (no a2)
        champJ[sm + p] = cj[pi];
        runUp[sm + p]  = ruv[pi];
    }
}

// one THREAD per point; grid: 2*B_*(N_/SPB) = 256 blocks of SPB=128 threads
__global__ __launch_bounds__(SPB) void cd_select(
        const float* __restrict__ xyz1, const float* __restrict__ xyz2,
        const float* __restrict__ champD, const unsigned int* __restrict__ champJ,
        const float* __restrict__ runUp, const float4* __restrict__ b4,
        double* __restrict__ dminArr, float* __restrict__ out) {
    const int ob  = blockIdx.x >> 5;                 // 32 blocks per (dir,b)
    const int c   = blockIdx.x & 31;
    const int dir = ob >> 2;
    const int b   = ob & 3;
    const int p0  = c * SPB;
    const float* A  = dir ? xyz2 : xyz1;
    const double tolk = dir ? TOL_K21 : TOL_K12;
    const float4* bb4 = b4 + (size_t)ob * N_;

    __shared__ float cDl[JSPLIT][SPB];               // 16 KiB (t-space)
    __shared__ unsigned int cJl[JSPLIT][SPB];        // 16 KiB
    __shared__ float rul[JSPLIT][SPB];               // 16 KiB

    const int t = threadIdx.x;
    for (int idx = t; idx < JSPLIT * SPB; idx += SPB) {
        const int s = idx >> 7, p = idx & (SPB - 1); // coalesced row loads
        const size_t g = ((size_t)ob * JSPLIT + s) * N_ + p0 + p;
        cDl[s][p] = champD[g];
        cJl[s][p] = champJ[g];
        rul[s][p] = runUp[g];
    }
    __syncthreads();

    const int p = p0 + t;
    const float* ap = A + ((size_t)b * N_ + p) * 3;
    const float x = ap[0], y = ap[1], z = ap[2];
    const float a2f = x * x + y * y + z * z;

    float m_t = FLT_MAX;
    #pragma unroll
    for (int s = 0; s < JSPLIT; ++s)
        m_t = fminf(m_t, cDl[s][t]);

    const float mind = m_t + a2f;                    // noisy global d32 min
    // widened skip threshold: covers t-cancellation noise (~4e-7*M) on both
    // sides plus the contract band (7.2e-8*M), >=3x margin; |mind| term keeps
    // it valid when a2f ~ 0 or mind < 0.
    const float skipthr = __fmaf_rn(4e-6f, a2f + fabsf(mind), mind);

    unsigned int candmask = 0, rescmask = 0;
    #pragma unroll
    for (int s = 0; s < JSPLIT; ++s) {
        if (cDl[s][t] + a2f <= skipthr) candmask |= (1u << s);
        if (rul[s][t] + a2f <= skipthr) rescmask |= (1u << s);
    }

    const double xd = (double)x, yd = (double)y, zd = (double)z;
    const double a2 = xd * xd + yd * yd + zd * zd;

    // pass A: exact f64 dmin over {champions of cand splits} U {rescan survivors}
    double dmin = 1.0e300;
    unsigned int mk = candmask;
    while (mk) {
        int s = __ffs(mk) - 1; mk &= mk - 1;
        float4 bv = bb4[cJl[s][t]];
        double ddx = xd - (double)bv.x, ddy = yd - (double)bv.y,
               ddz = zd - (double)bv.z;
        dmin = fmin(dmin, fma(ddx, ddx, fma(ddy, ddy, ddz * ddz)));
    }
    mk = rescmask;
    while (mk) {                                     // rare
        int s = __ffs(mk) - 1; mk &= mk - 1;
        for (int j = s * CHUNK; j < (s + 1) * CHUNK; ++j) {
            float4 bv = bb4[j];
            float dx = x - bv.x, dy = y - bv.y, dz = z - bv.z;
            float d32 = __fmaf_rn(dx, dx, __fmaf_rn(dy, dy, dz * dz));
            float thr = __fmaf_rn(2e-7f, a2f + bv.w, skipthr);
            if (d32 <= thr) {
                double ddx = xd - (double)bv.x, ddy = yd - (double)bv.y,
                       ddz = zd - (double)bv.z;
                dmin = fmin(dmin, fma(ddx, ddx, fma(ddy, ddy, ddz * ddz)));
            }
        }
    }

    // pass B: contract pick over the same set (extras provably fail the test)
    unsigned int pick = 0xFFFFFFFFu;
    mk = candmask;
    while (mk) {
        int s = __ffs(mk) - 1; mk &= mk - 1;
        unsigned int j = cJl[s][t];
        float4 bv = bb4[j];
        double bxd = (double)bv.x, byd = (double)bv.y, bzd = (double)bv.z;
        double ddx = xd - bxd, ddy = yd - byd, ddz = zd - bzd;
        double d64 = fma(ddx, ddx, fma(ddy, ddy, ddz * ddz));
        double M   = a2 + (bxd * bxd + byd * byd + bzd * bzd);
        if (d64 <= fma(tolk, M, dmin)) pick = (j < pick) ? j : pick;
    }
    mk = rescmask;
    while (mk) {
        int s = __ffs(mk) - 1; mk &= mk - 1;
        for (int j = s * CHUNK; j < (s + 1) * CHUNK; ++j) {
            float4 bv = bb4[j];
            float dx = x - bv.x, dy = y - bv.y, dz = z - bv.z;
            float d32 = __fmaf_rn(dx, dx, __fmaf_rn(dy, dy, dz * dz));
            float thr = __fmaf_rn(2e-7f, a2f + bv.w, skipthr);
            if (d32 <= thr) {
                double bxd = (double)bv.x, byd = (double)bv.y, bzd = (double)bv.z;
                double ddx = xd - bxd, ddy = yd - byd, ddz = zd - bzd;
                double d64 = fma(ddx, ddx, fma(ddy, ddy, ddz * ddz));
                double M   = a2 + (bxd * bxd + byd * byd + bzd * bzd);
                if (d64 <= fma(tolk, M, dmin))
                    pick = ((unsigned int)j < pick) ? (unsigned int)j : pick;
            }
        }
    }

    dminArr[(size_t)ob * N_ + p] = dmin;
    const size_t obase = (dir == 0) ? (1 + (size_t)b * N_)
                                    : (1 + (size_t)B_ * N_ + (size_t)b * N_);
    out[obase + p] = (float)pick;
}

__global__ __launch_bounds__(256) void cd_finalize(
        const double* __restrict__ dminArr, float* __restrict__ out,
        double* __restrict__ loss_part) {
    const int b = blockIdx.x;
    const int t = threadIdx.x;

    double sum12 = 0.0, max12 = -1.0e300, sum21 = 0.0;
    for (int n = t; n < N_; n += 256) {
        double d12 = dminArr[(size_t)b * N_ + n];
        double d21 = dminArr[((size_t)B_ + b) * N_ + n];
        sum12 += d12;
        max12 = fmax(max12, d12);
        sum21 += d21;
    }
    __shared__ double s1[256], s2[256], s3[256];
    s1[t] = sum12; s2[t] = max12; s3[t] = sum21;
    __syncthreads();
    for (int off = 128; off > 0; off >>= 1) {
        if (t < off) {
            s1[t] += s1[t + off];
            s2[t]  = fmax(s2[t], s2[t + off]);
            s3[t] += s3[t + off];
        }
        __syncthreads();
    }
    if (t == 0) {
        loss_part[b] = s1[0] / (double)N_ + BETA_ * s2[0]
                     + (GAMMA_ + DELTA_ * (double)N_) * (s3[0] / (double)N_);
    }
}

__global__ void cd_loss(const double* __restrict__ loss_part,
                        float* __restrict__ out) {
    if (blockIdx.x == 0 && threadIdx.x == 0) {
        double s = 0.0;
        for (int b = 0; b < B_; ++b) s += loss_part[b];  // fixed order
        out[0] = (float)(s / (double)B_);
    }
}

extern "C" void kernel_launch(void* const* d_in, const int* in_sizes, int n_in,
                              void* d_out, int out_size, void* d_ws, size_t ws_size,
                              hipStream_t stream) {
    const float* xyz1 = (const float*)d_in[0];
    const float* xyz2 = (const float*)d_in[1];
    float* out = (float*)d_out;

    const size_t NP = (size_t)2 * B_ * N_;       // 32768 points
    double* dminArr   = (double*)d_ws;           // NP doubles (256 KiB)
    double* loss_part = dminArr + NP;            // B_ doubles
    float4* b4 = (float4*)(loss_part + B_);      // NP float4 (512 KiB)
    float* champD = (float*)(b4 + NP);           // NP*JSPLIT f32 (4 MiB)
    unsigned int* champJ = (unsigned int*)(champD + NP * JSPLIT);  // 4 MiB
    float* runUp = (float*)(champJ + NP * JSPLIT);                 // 4 MiB

    dim3 grid(TILES * B_ * 2, JSPLIT);
    cd_min32<<<grid, PTS, 0, stream>>>(xyz1, xyz2, champD, champJ, runUp, b4);

    cd_select<<<(int)(NP / SPB), SPB, 0, stream>>>(
        xyz1, xyz2, champD, champJ, runUp, b4, dminArr, out);

    cd_finalize<<<B_, 256, 0, stream>>>(dminArr, out, loss_part);
    cd_loss<<<1, 64, 0, stream>>>(loss_part, out);
}

// Round 28
// 47.901 us; speedup vs baseline: 1.2493x; 1.0952x over previous
//
#include <hip/hip_runtime.h>
#include <stdint.h>
#include <float.h>

// Chamfer distance, B=4, N=M=4096, 3D fp32.
// Outputs (flat, float32): [0] loss, [1..16384] idx12 (float), [16385..32768] idx21.
//
// SEMANTIC CONTRACT (validated R14-R27, absmax 0.0 — do not change):
//   d in f64: d = fma(dx,dx, fma(dy,dy, dz*dz)), dx = x - bx (f64-promoted f32)
//   pick = smallest index j with d_j <= fma(TOL_K(dir), a2 + b2_j, dmin)
//     (a2, b2_j in f64 from promoted f32 coords)
//   K12 = 0.6*2^-23, K21 = 0.   dmin = exact f64 min over prefilter survivors.
//   Prefilter (R16-proven 2x margin): survivor iff
//     d32 <= fma(2e-7, a2f+b2f_j, me), me = m*(1+2e-6), m = global f32 min.
//   Split skip (R18-validated): skip iff splitmin > (me + 7e-7*a2f)*(1+4e-6).
//
// R28: REVERT to R24 (session best, 48.478us). Global timing model fitted over
// all 14 passing rounds: dur = max(~48.5us harness path [268MB per-replay fill
// at 81% HBM peak + graph overhead], kernel chain). R18-R25 chains (20-48us)
// all pinned at 48.5-51 (hidden under fill); R22/R26/R27 chains >48 poke out
// by their excess. R24's chain <= 48 => dur = harness floor. Expect ~48.5;
// if confirmed, session is at the harness-set roofline.

constexpr int B_ = 4;
constexpr int N_ = 4096;
constexpr int PTS = 256;
constexpr int PPT = 8;
constexpr int TILES = N_ / (PTS * PPT);  // 2
constexpr int JSPLIT = 32;
constexpr int CHUNK = N_ / JSPLIT;       // 128
constexpr double EPS32 = 1.1920928955078125e-7;  // 2^-23
constexpr double TOL_K12 = 0.6 * EPS32;
constexpr double TOL_K21 = 0.0;
constexpr double BETA_ = 1.0;
constexpr double GAMMA_ = 1.0;
constexpr double DELTA_ = 0.0;

// grid: (TILES*B_*2, JSPLIT)
__global__ __launch_bounds__(256) void cd_min32(
        const float* __restrict__ xyz1, const float* __restrict__ xyz2,
        unsigned int* __restrict__ splitmin, float4* __restrict__ b4) {
    const int tile  = blockIdx.x % TILES;
    const int b     = (blockIdx.x / TILES) % B_;
    const int dir   = blockIdx.x / (TILES * B_);
    const int split = blockIdx.y;
    const float* A  = dir ? xyz2 : xyz1;
    const float* Bc = dir ? xyz1 : xyz2;
    const size_t ob = (size_t)dir * B_ + b;

    __shared__ float4 s[CHUNK];          // 2 KiB
    const float* bbase = Bc + ((size_t)b * N_ + (size_t)split * CHUNK) * 3;
    if (threadIdx.x < CHUNK) {
        int j = threadIdx.x;
        float bx = bbase[3 * j], by = bbase[3 * j + 1], bz = bbase[3 * j + 2];
        float b2 = bx * bx + by * by + bz * bz;   // prefilter-only (margin ok)
        float4 v = make_float4(bx, by, bz, b2);
        s[j] = v;
        if (tile == 0)                    // one writer per (dir,b,split)
            b4[ob * N_ + (size_t)split * CHUNK + j] = v;
    }
    __syncthreads();

    float px[PPT], py[PPT], pz[PPT], mn[PPT];
    #pragma unroll
    for (int pi = 0; pi < PPT; ++pi) {
        const int p = tile * (PTS * PPT) + pi * PTS + threadIdx.x;
        const float* ap = A + ((size_t)b * N_ + p) * 3;
        px[pi] = ap[0]; py[pi] = ap[1]; pz[pi] = ap[2];
        mn[pi] = FLT_MAX;
    }

    #pragma unroll 4
    for (int j = 0; j < CHUNK; ++j) {
        float4 bv = s[j];
        #pragma unroll
        for (int pi = 0; pi < PPT; ++pi) {
            float dx = px[pi] - bv.x, dy = py[pi] - bv.y, dz = pz[pi] - bv.z;
            mn[pi] = fminf(mn[pi],
                           __fmaf_rn(dx, dx, __fmaf_rn(dy, dy, dz * dz)));
        }
    }

    const size_t sm = (ob * JSPLIT + split) * N_;
    #pragma unroll
    for (int pi = 0; pi < PPT; ++pi) {
        const int p = tile * (PTS * PPT) + pi * PTS + threadIdx.x;
        splitmin[sm + p] = __float_as_uint(mn[pi]);   // block-owned store
    }
}

// one wave per point; grid: (2*B_*N_)/4 = 8192 blocks of 256 (4 waves/block)
__global__ __launch_bounds__(256) void cd_select(
        const float* __restrict__ xyz1, const float* __restrict__ xyz2,
        const unsigned int* __restrict__ splitmin, const float4* __restrict__ b4,
        double* __restrict__ dminArr, float* __restrict__ out) {
    const int W0   = blockIdx.x * 4;                 // first point id of block
    const int dir  = W0 / (B_ * N_);
    const int b    = (W0 / N_) % B_;
    const int p0   = W0 % N_;
    const float* A  = dir ? xyz2 : xyz1;
    const double tolk = dir ? TOL_K21 : TOL_K12;
    const size_t ob = (size_t)dir * B_ + b;
    const float4* bb4 = b4 + ob * N_;

    __shared__ unsigned int lt[4][32];               // 512 B panel

    // phase 1: cooperative panel load
    if (threadIdx.x < 128) {
        const int s  = threadIdx.x >> 2;
        const int pi = threadIdx.x & 3;
        lt[pi][s] = splitmin[(ob * JSPLIT + s) * N_ + p0 + pi];
    }
    __syncthreads();

    const int wv   = threadIdx.x >> 6;               // wave -> point p0+wv
    const int lane = threadIdx.x & 63;
    const int p    = p0 + wv;
    const int W    = W0 + wv;

    const float* ap = A + ((size_t)b * N_ + p) * 3;
    const float x = ap[0], y = ap[1], z = ap[2];
    const float a2f = x * x + y * y + z * z;

    // m = min over 32 per-split minima (== global f32 min, bit-identical)
    const int l32 = lane & 31;
    const float sv = __uint_as_float(lt[wv][l32]);
    float m = sv;
    #pragma unroll
    for (int off = 1; off < 32; off <<= 1)
        m = fminf(m, __shfl_xor(m, off));

    const float me = __fmaf_rn(2e-6f, m, m);         // m*(1+2e-6)
    const float skipthr = (me + 7e-7f * a2f) * (1.0f + 4e-6f);
    unsigned int mask = (unsigned int)__ballot(lane < 32 && sv <= skipthr);

    const double xd = (double)x, yd = (double)y, zd = (double)z;
    const double a2 = xd * xd + yd * yd + zd * zd;

    // pass 1: f64 dmin over prefilter survivors (true argmin provably among them)
    double dmin = 1.0e300;
    unsigned int mk = mask;
    while (mk) {
        int s = __ffs(mk) - 1; mk &= mk - 1;
        int j0 = s * CHUNK + lane;
        float4 bv0 = bb4[j0];
        float4 bv1 = bb4[j0 + 64];
        #pragma unroll
        for (int k = 0; k < 2; ++k) {
            float4 bv = k ? bv1 : bv0;
            float dx = x - bv.x, dy = y - bv.y, dz = z - bv.z;
            float d32 = __fmaf_rn(dx, dx, __fmaf_rn(dy, dy, dz * dz));
            float thr = __fmaf_rn(2e-7f, a2f + bv.w, me);
            if (d32 <= thr) {
                double ddx = xd - (double)bv.x, ddy = yd - (double)bv.y,
                       ddz = zd - (double)bv.z;
                dmin = fmin(dmin, fma(ddx, ddx, fma(ddy, ddy, ddz * ddz)));
            }
        }
    }
    #pragma unroll
    for (int off = 1; off < 64; off <<= 1)
        dmin = fmin(dmin, __shfl_xor(dmin, off));

    // pass 2: smallest index with d64 <= fma(tolk, M64, dmin)  [contract]
    unsigned int pick = 0xFFFFFFFFu;
    mk = mask;
    while (mk) {
        int s = __ffs(mk) - 1; mk &= mk - 1;
        int j0 = s * CHUNK + lane;
        float4 bv0 = bb4[j0];
        float4 bv1 = bb4[j0 + 64];
        #pragma unroll
        for (int k = 0; k < 2; ++k) {
            float4 bv = k ? bv1 : bv0;
            int j = j0 + k * 64;
            float dx = x - bv.x, dy = y - bv.y, dz = z - bv.z;
            float d32 = __fmaf_rn(dx, dx, __fmaf_rn(dy, dy, dz * dz));
            float thr = __fmaf_rn(2e-7f, a2f + bv.w, me);
            if (d32 <= thr) {
                double bxd = (double)bv.x, byd = (double)bv.y, bzd = (double)bv.z;
                double ddx = xd - bxd, ddy = yd - byd, ddz = zd - bzd;
                double d64 = fma(ddx, ddx, fma(ddy, ddy, ddz * ddz));
                double M   = a2 + (bxd * bxd + byd * byd + bzd * bzd);
                if (d64 <= fma(tolk, M, dmin))
                    pick = (pick < (unsigned int)j) ? pick : (unsigned int)j;
            }
        }
    }
    #pragma unroll
    for (int off = 1; off < 64; off <<= 1) {
        unsigned int o2 = (unsigned int)__shfl_xor((int)pick, off);
        pick = (o2 < pick) ? o2 : pick;
    }

    if (lane == 0) {
        dminArr[W] = dmin;
        const size_t obase = (dir == 0) ? (1 + (size_t)b * N_)
                                        : (1 + (size_t)B_ * N_ + (size_t)b * N_);
        out[obase + p] = (float)pick;
    }
}

__global__ __launch_bounds__(256) void cd_finalize(
        const double* __restrict__ dminArr, float* __restrict__ out,
        double* __restrict__ loss_part) {
    const int b = blockIdx.x;
    const int t = threadIdx.x;

    double sum12 = 0.0, max12 = -1.0e300, sum21 = 0.0;
    for (int n = t; n < N_; n += 256) {
        double d12 = dminArr[(size_t)b * N_ + n];
        double d21 = dminArr[((size_t)B_ + b) * N_ + n];
        sum12 += d12;
        max12 = fmax(max12, d12);
        sum21 += d21;
    }
    __shared__ double s1[256], s2[256], s3[256];
    s1[t] = sum12; s2[t] = max12; s3[t] = sum21;
    __syncthreads();
    for (int off = 128; off > 0; off >>= 1) {
        if (t < off) {
            s1[t] += s1[t + off];
            s2[t]  = fmax(s2[t], s2[t + off]);
            s3[t] += s3[t + off];
        }
        __syncthreads();
    }
    if (t == 0) {
        loss_part[b] = s1[0] / (double)N_ + BETA_ * s2[0]
                     + (GAMMA_ + DELTA_ * (double)N_) * (s3[0] / (double)N_);
    }
}

__global__ void cd_loss(const double* __restrict__ loss_part,
                        float* __restrict__ out) {
    if (blockIdx.x == 0 && threadIdx.x == 0) {
        double s = 0.0;
        for (int b = 0; b < B_; ++b) s += loss_part[b];  // fixed order
        out[0] = (float)(s / (double)B_);
    }
}

extern "C" void kernel_launch(void* const* d_in, const int* in_sizes, int n_in,
                              void* d_out, int out_size, void* d_ws, size_t ws_size,
                              hipStream_t stream) {
    const float* xyz1 = (const float*)d_in[0];
    const float* xyz2 = (const float*)d_in[1];
    float* out = (float*)d_out;

    const size_t NP = (size_t)2 * B_ * N_;       // 32768 points
    double* dminArr   = (double*)d_ws;           // NP doubles
    double* loss_part = dminArr + NP;            // B_ doubles
    unsigned int* splitmin = (unsigned int*)(loss_part + B_);  // NP*JSPLIT (4 MiB)
    float4* b4 = (float4*)(splitmin + NP * JSPLIT);            // 512 KiB

    dim3 grid(TILES * B_ * 2, JSPLIT);
    cd_min32<<<grid, PTS, 0, stream>>>(xyz1, xyz2, splitmin, b4);

    cd_select<<<(int)(NP / 4), 256, 0, stream>>>(xyz1, xyz2, splitmin, b4,
                                                 dminArr, out);

    cd_finalize<<<B_, 256, 0, stream>>>(dminArr, out, loss_part);
    cd_loss<<<1, 64, 0, stream>>>(loss_part, out);
}